// Round 1
// baseline (684.713 us; speedup 1.0000x reference)
//
#include <hip/hip_runtime.h>
#include <hip/hip_bf16.h>

#define N_NODES 10000
#define FIN 512
#define FOUT 64
#define NP 10016            // padded row length for h^T (bf16) and s2
#define LEAKY_ALPHA 0.2f
#define TOTAL_STEPS 313     // ceil(10000/32); step 312 is the 16-wide tail

typedef __attribute__((ext_vector_type(8))) short short8;
typedef __attribute__((ext_vector_type(4))) float f32x4;
typedef __attribute__((ext_vector_type(8))) __bf16 bf16x8;

static __device__ __forceinline__ unsigned short f2bf(float f) {
  unsigned u = __builtin_bit_cast(unsigned, f);
  u += 0x7FFFu + ((u >> 16) & 1u);          // RNE
  return (unsigned short)(u >> 16);
}
static __device__ __forceinline__ float bf2f(unsigned short s) {
  unsigned u = ((unsigned)s) << 16;
  return __builtin_bit_cast(float, u);
}
// order-preserving f32 -> u32 map (for atomicMax); memset-0 init == -NaN (below everything)
static __device__ __forceinline__ unsigned enc_f32(float f) {
  unsigned u = __builtin_bit_cast(unsigned, f);
  return (u & 0x80000000u) ? ~u : (u | 0x80000000u);
}
static __device__ __forceinline__ float dec_f32(unsigned u) {
  unsigned b = (u & 0x80000000u) ? (u & 0x7FFFFFFFu) : ~u;
  return __builtin_bit_cast(float, b);
}

// ---------------- Kernel A: h = X@W (fp32), s1=h@a1, s2=h@a2, h^T in bf16 ----------------
// 1 wave per block, 8 rows per block. grid = 1250.
__global__ __launch_bounds__(64) void gat_h(
    const float* __restrict__ input, const float* __restrict__ W,
    const float* __restrict__ a, float* __restrict__ s1,
    float* __restrict__ s2, unsigned short* __restrict__ hbT,
    unsigned int* __restrict__ maxbits) {
  __shared__ float in_lds[8 * FIN];
  const int l = threadIdx.x;
  const int rb = blockIdx.x * 8;

  const float4* src = (const float4*)(input + (size_t)rb * FIN);
  float4* dst = (float4*)in_lds;
#pragma unroll
  for (int v = 0; v < 16; ++v) dst[l + 64 * v] = src[l + 64 * v];
  __syncthreads();

  float acc[8] = {0.f, 0.f, 0.f, 0.f, 0.f, 0.f, 0.f, 0.f};
  for (int k4 = 0; k4 < FIN / 4; ++k4) {
    float w0 = W[(k4 * 4 + 0) * FOUT + l];
    float w1 = W[(k4 * 4 + 1) * FOUT + l];
    float w2 = W[(k4 * 4 + 2) * FOUT + l];
    float w3 = W[(k4 * 4 + 3) * FOUT + l];
#pragma unroll
    for (int r = 0; r < 8; ++r) {
      float4 iv = *(const float4*)&in_lds[r * FIN + k4 * 4];  // LDS broadcast
      acc[r] = fmaf(iv.x, w0, fmaf(iv.y, w1, fmaf(iv.z, w2, fmaf(iv.w, w3, acc[r]))));
    }
  }

  // h^T (bf16): hbT[f][i], 8 consecutive i per lane -> one 16B store
  short8 pk;
#pragma unroll
  for (int r = 0; r < 8; ++r) pk[r] = (short)f2bf(acc[r]);
  *(short8*)(hbT + (size_t)l * NP + rb) = pk;

  const float a1l = a[l], a2l = a[FOUT + l];
  float m1 = -1e30f, m2 = -1e30f;
#pragma unroll
  for (int r = 0; r < 8; ++r) {
    float v1 = acc[r] * a1l, v2 = acc[r] * a2l;
#pragma unroll
    for (int off = 32; off > 0; off >>= 1) {
      v1 += __shfl_xor(v1, off);
      v2 += __shfl_xor(v2, off);
    }
    if (l == 0) { s1[rb + r] = v1; s2[rb + r] = v2; }
    m1 = fmaxf(m1, v1);
    m2 = fmaxf(m2, v2);
  }
  if (l == 0) {
    atomicMax(maxbits + 0, enc_f32(m1));
    atomicMax(maxbits + 1, enc_f32(m2));
  }
}

// ---------------- Kernel B: fused masked-softmax x h (the 400 MB adj stream) ----------------
// 1 wave per block. blockIdx.x = 16-row tile (625), blockIdx.y = K-split chunk.
__global__ __launch_bounds__(64) void gat_attn(
    const int* __restrict__ adj, const float* __restrict__ s1,
    const float* __restrict__ s2, const unsigned short* __restrict__ hbT,
    const unsigned int* __restrict__ maxbits,
    float* __restrict__ num_part, float* __restrict__ den_part,
    int steps_per_chunk) {
  const int l = threadIdx.x;
  const int r = l & 15;        // A-frag row / adj row within tile
  const int g = l >> 4;        // k-group
  const int kb = g * 8;        // k base within 32-step
  const int row_base = blockIdx.x * 16;
  const int split = blockIdx.y;

  const float msum = dec_f32(maxbits[0]) + dec_f32(maxbits[1]);
  const float m = (msum > 0.f) ? msum : LEAKY_ALPHA * msum;  // leaky(max s1 + max s2) >= all e

  int sb = split * steps_per_chunk;
  int se = sb + steps_per_chunk;
  if (se > TOTAL_STEPS) se = TOTAL_STEPS;
  bool has_tail = false;
  if (se == TOTAL_STEPS) { has_tail = true; se = TOTAL_STEPS - 1; }

  const float s1r = s1[row_base + r];
  const int* __restrict__ adjp = adj + (size_t)(row_base + r) * N_NODES;
  const unsigned short* __restrict__ bp = hbT + (size_t)r * NP;

  f32x4 acc0 = {0.f, 0.f, 0.f, 0.f};
  f32x4 acc1 = {0.f, 0.f, 0.f, 0.f};
  f32x4 acc2 = {0.f, 0.f, 0.f, 0.f};
  f32x4 acc3 = {0.f, 0.f, 0.f, 0.f};
  float den_acc = 0.f;

  for (int t = sb; t < se; ++t) {
    const int j = t * 32 + kb;
    int4 av0 = *(const int4*)(adjp + j);
    int4 av1 = *(const int4*)(adjp + j + 4);
    float4 sv0 = *(const float4*)(s2 + j);
    float4 sv1 = *(const float4*)(s2 + j + 4);
    short8 b0 = *(const short8*)(bp + j);
    short8 b1 = *(const short8*)(bp + 16 * NP + j);
    short8 b2 = *(const short8*)(bp + 32 * NP + j);
    short8 b3 = *(const short8*)(bp + 48 * NP + j);

    float sef[8] = {sv0.x, sv0.y, sv0.z, sv0.w, sv1.x, sv1.y, sv1.z, sv1.w};
    int ad[8] = {av0.x, av0.y, av0.z, av0.w, av1.x, av1.y, av1.z, av1.w};
    short8 af;
#pragma unroll
    for (int e = 0; e < 8; ++e) {
      float ee = s1r + sef[e];
      ee = (ee >= 0.f) ? ee : LEAKY_ALPHA * ee;
      float w = (ad[e] > 0) ? __expf(ee - m) : 0.f;
      unsigned short wb = f2bf(w);
      af[e] = (short)wb;
      den_acc += bf2f(wb);  // denominator = sum of the SAME bf16-rounded weights
    }
    bf16x8 av = __builtin_bit_cast(bf16x8, af);
    acc0 = __builtin_amdgcn_mfma_f32_16x16x32_bf16(av, __builtin_bit_cast(bf16x8, b0), acc0, 0, 0, 0);
    acc1 = __builtin_amdgcn_mfma_f32_16x16x32_bf16(av, __builtin_bit_cast(bf16x8, b1), acc1, 0, 0, 0);
    acc2 = __builtin_amdgcn_mfma_f32_16x16x32_bf16(av, __builtin_bit_cast(bf16x8, b2), acc2, 0, 0, 0);
    acc3 = __builtin_amdgcn_mfma_f32_16x16x32_bf16(av, __builtin_bit_cast(bf16x8, b3), acc3, 0, 0, 0);
  }

  if (has_tail) {  // j0 = 9984: only 16 valid j -> k-groups 0,1 active, others contribute 0
    short8 af = {0, 0, 0, 0, 0, 0, 0, 0};
    short8 b0 = {0, 0, 0, 0, 0, 0, 0, 0};
    short8 b1 = {0, 0, 0, 0, 0, 0, 0, 0};
    short8 b2 = {0, 0, 0, 0, 0, 0, 0, 0};
    short8 b3 = {0, 0, 0, 0, 0, 0, 0, 0};
    if (g < 2) {
      const int j = 9984 + kb;
      int4 av0 = *(const int4*)(adjp + j);
      int4 av1 = *(const int4*)(adjp + j + 4);
      float4 sv0 = *(const float4*)(s2 + j);
      float4 sv1 = *(const float4*)(s2 + j + 4);
      b0 = *(const short8*)(bp + j);
      b1 = *(const short8*)(bp + 16 * NP + j);
      b2 = *(const short8*)(bp + 32 * NP + j);
      b3 = *(const short8*)(bp + 48 * NP + j);
      float sef[8] = {sv0.x, sv0.y, sv0.z, sv0.w, sv1.x, sv1.y, sv1.z, sv1.w};
      int ad[8] = {av0.x, av0.y, av0.z, av0.w, av1.x, av1.y, av1.z, av1.w};
#pragma unroll
      for (int e = 0; e < 8; ++e) {
        float ee = s1r + sef[e];
        ee = (ee >= 0.f) ? ee : LEAKY_ALPHA * ee;
        float w = (ad[e] > 0) ? __expf(ee - m) : 0.f;
        unsigned short wb = f2bf(w);
        af[e] = (short)wb;
        den_acc += bf2f(wb);
      }
    }
    bf16x8 av = __builtin_bit_cast(bf16x8, af);
    acc0 = __builtin_amdgcn_mfma_f32_16x16x32_bf16(av, __builtin_bit_cast(bf16x8, b0), acc0, 0, 0, 0);
    acc1 = __builtin_amdgcn_mfma_f32_16x16x32_bf16(av, __builtin_bit_cast(bf16x8, b1), acc1, 0, 0, 0);
    acc2 = __builtin_amdgcn_mfma_f32_16x16x32_bf16(av, __builtin_bit_cast(bf16x8, b2), acc2, 0, 0, 0);
    acc3 = __builtin_amdgcn_mfma_f32_16x16x32_bf16(av, __builtin_bit_cast(bf16x8, b3), acc3, 0, 0, 0);
  }

  // denominator: reduce the 4 lanes sharing row r
  den_acc += __shfl_xor(den_acc, 16);
  den_acc += __shfl_xor(den_acc, 32);
  if (l < 16) den_part[(size_t)split * N_NODES + row_base + r] = den_acc;

  // numerator: C/D layout col = l&15 (+16n), row = g*4 + q
  float* np_ = num_part + ((size_t)split * N_NODES + row_base) * FOUT;
#pragma unroll
  for (int q = 0; q < 4; ++q) {
    const int orow = g * 4 + q;
    np_[orow * FOUT + 0 + r] = acc0[q];
    np_[orow * FOUT + 16 + r] = acc1[q];
    np_[orow * FOUT + 32 + r] = acc2[q];
    np_[orow * FOUT + 48 + r] = acc3[q];
  }
}

// ---------------- Kernel C: reduce partials, normalize, ELU ----------------
__global__ __launch_bounds__(256) void gat_out(
    const float* __restrict__ num_part, const float* __restrict__ den_part,
    const unsigned short* __restrict__ hbT, float* __restrict__ out, int S) {
  const int idx = blockIdx.x * 256 + threadIdx.x;
  if (idx >= N_NODES * FOUT) return;
  const int i = idx >> 6, f = idx & 63;
  float den = 0.f, num = 0.f;
  for (int s = 0; s < S; ++s) {
    den += den_part[(size_t)s * N_NODES + i];
    num += num_part[(size_t)s * N_NODES * FOUT + idx];
  }
  float v;
  if (den > 0.f) {
    v = num / den;
  } else {
    // row with no neighbors: softmax(all NEG_BIG) = uniform -> mean of h
    float sum = 0.f;
    for (int j = 0; j < N_NODES; ++j) sum += bf2f(hbT[(size_t)f * NP + j]);
    v = sum / (float)N_NODES;
  }
  out[idx] = (v > 0.f) ? v : (__expf(v) - 1.f);
}

extern "C" void kernel_launch(void* const* d_in, const int* in_sizes, int n_in,
                              void* d_out, int out_size, void* d_ws, size_t ws_size,
                              hipStream_t stream) {
  const float* input = (const float*)d_in[0];
  const float* W = (const float*)d_in[1];
  const float* a = (const float*)d_in[2];
  const int* adj = (const int*)d_in[3];
  float* out = (float*)d_out;

  int S = 4;  // K-splits for occupancy; fall back to 1 if workspace is tight
  {
    size_t need4 = (size_t)4 * N_NODES * FOUT * 4 + (size_t)4 * N_NODES * 4 + 64 +
                   (size_t)N_NODES * 4 + (size_t)NP * 4 + (size_t)FOUT * NP * 2 + 256;
    if (ws_size < need4) S = 1;
  }

  char* p = (char*)d_ws;
  float* num_part = (float*)p;               p += (size_t)S * N_NODES * FOUT * 4;
  float* den_part = (float*)p;               p += (size_t)S * N_NODES * 4;
  unsigned int* maxbits = (unsigned int*)p;  p += 64;  // 8B used + pad (keeps next 16B-aligned)
  float* s1 = (float*)p;                     p += (size_t)N_NODES * 4;
  float* s2 = (float*)p;                     p += (size_t)NP * 4;
  unsigned short* hbT = (unsigned short*)p;  // FOUT * NP bf16

  // zero the accumulation targets (+ maxbits); ws is poisoned 0xAA before each call
  size_t zero_bytes = (size_t)S * N_NODES * FOUT * 4 + (size_t)S * N_NODES * 4 + 8;
  hipMemsetAsync(d_ws, 0, zero_bytes, stream);

  hipLaunchKernelGGL(gat_h, dim3(N_NODES / 8), dim3(64), 0, stream,
                     input, W, a, s1, s2, hbT, maxbits);

  int steps_per_chunk = (TOTAL_STEPS + S - 1) / S;
  hipLaunchKernelGGL(gat_attn, dim3(N_NODES / 16, S), dim3(64), 0, stream,
                     adj, s1, s2, hbT, maxbits, num_part, den_part, steps_per_chunk);

  hipLaunchKernelGGL(gat_out, dim3((N_NODES * FOUT + 255) / 256), dim3(256), 0, stream,
                     num_part, den_part, hbT, out, S);
}

// Round 3
// 676.469 us; speedup vs baseline: 1.0122x; 1.0122x over previous
//
#include <hip/hip_runtime.h>
#include <hip/hip_bf16.h>

#define N_NODES 10000
#define FIN 512
#define FOUT 64
#define NP 10016            // padded row length for h^T (bf16) and s2
#define TOTAL_STEPS 313     // ceil(10000/32); step 312 is the 16-wide tail

typedef __attribute__((ext_vector_type(8))) short short8;
typedef __attribute__((ext_vector_type(4))) float f32x4;
typedef __attribute__((ext_vector_type(8))) __bf16 bf16x8;
typedef __attribute__((ext_vector_type(4))) unsigned int uint4v;

static __device__ __forceinline__ unsigned short f2bf(float f) {
  unsigned u = __builtin_bit_cast(unsigned, f);
  u += 0x7FFFu + ((u >> 16) & 1u);          // RNE
  return (unsigned short)(u >> 16);
}
static __device__ __forceinline__ float bf2f(unsigned short s) {
  unsigned u = ((unsigned)s) << 16;
  return __builtin_bit_cast(float, u);
}
// order-preserving f32 -> u32 map (for atomicMax); memset-0 init == below everything
static __device__ __forceinline__ unsigned enc_f32(float f) {
  unsigned u = __builtin_bit_cast(unsigned, f);
  return (u & 0x80000000u) ? ~u : (u | 0x80000000u);
}
static __device__ __forceinline__ float dec_f32(unsigned u) {
  unsigned b = (u & 0x80000000u) ? (u & 0x7FFFFFFFu) : ~u;
  return __builtin_bit_cast(float, b);
}

// weight pair: leaky_relu via max(x, 0.2x); adj in {0,1} -> multiply; RNE pack into u32
static __device__ __forceinline__ unsigned wpair(float s1r, float sA, float sB,
                                                 int adA, int adB, float m) {
  float eA = s1r + sA, eB = s1r + sB;
  eA = fmaxf(eA, 0.2f * eA);
  eB = fmaxf(eB, 0.2f * eB);
  float wA = __expf(eA - m) * (float)adA;
  float wB = __expf(eB - m) * (float)adB;
  return ((unsigned)f2bf(wB) << 16) | (unsigned)f2bf(wA);
}

// ---------------- Kernel A: h = X@W (fp32), s1=h@a1, s2=h@a2, h^T in bf16 ----------------
__global__ __launch_bounds__(64) void gat_h(
    const float* __restrict__ input, const float* __restrict__ W,
    const float* __restrict__ a, float* __restrict__ s1,
    float* __restrict__ s2, unsigned short* __restrict__ hbT,
    unsigned int* __restrict__ maxbits) {
  __shared__ float in_lds[8 * FIN];
  const int l = threadIdx.x;
  const int rb = blockIdx.x * 8;

  const float4* src = (const float4*)(input + (size_t)rb * FIN);
  float4* dst = (float4*)in_lds;
#pragma unroll
  for (int v = 0; v < 16; ++v) dst[l + 64 * v] = src[l + 64 * v];
  __syncthreads();

  float acc[8] = {0.f, 0.f, 0.f, 0.f, 0.f, 0.f, 0.f, 0.f};
  for (int k4 = 0; k4 < FIN / 4; ++k4) {
    float w0 = W[(k4 * 4 + 0) * FOUT + l];
    float w1 = W[(k4 * 4 + 1) * FOUT + l];
    float w2 = W[(k4 * 4 + 2) * FOUT + l];
    float w3 = W[(k4 * 4 + 3) * FOUT + l];
#pragma unroll
    for (int r = 0; r < 8; ++r) {
      float4 iv = *(const float4*)&in_lds[r * FIN + k4 * 4];  // uniform LDS broadcast
      acc[r] = fmaf(iv.x, w0, fmaf(iv.y, w1, fmaf(iv.z, w2, fmaf(iv.w, w3, acc[r]))));
    }
  }

  short8 pk;
#pragma unroll
  for (int r = 0; r < 8; ++r) pk[r] = (short)f2bf(acc[r]);
  *(short8*)(hbT + (size_t)l * NP + rb) = pk;

  const float a1l = a[l], a2l = a[FOUT + l];
  float m1 = -1e30f, m2 = -1e30f;
#pragma unroll
  for (int r = 0; r < 8; ++r) {
    float v1 = acc[r] * a1l, v2 = acc[r] * a2l;
#pragma unroll
    for (int off = 32; off > 0; off >>= 1) {
      v1 += __shfl_xor(v1, off);
      v2 += __shfl_xor(v2, off);
    }
    if (l == 0) { s1[rb + r] = v1; s2[rb + r] = v2; }
    m1 = fmaxf(m1, v1);
    m2 = fmaxf(m2, v2);
  }
  if (l == 0) {
    atomicMax(maxbits + 0, enc_f32(m1));
    atomicMax(maxbits + 1, enc_f32(m2));
  }
}

// ---------------- Kernel B: fused masked-softmax x h (the 400 MB adj stream) ----------------
// 1 wave per block. blockIdx.x = 16-row tile (625), blockIdx.y = K-split chunk.
// Register double-buffered loads; denominator via MFMA against all-ones B.
__global__ __launch_bounds__(64) void gat_attn(
    const int* __restrict__ adj, const float* __restrict__ s1,
    const float* __restrict__ s2, const unsigned short* __restrict__ hbT,
    const unsigned int* __restrict__ maxbits,
    float* __restrict__ num_part, float* __restrict__ den_part,
    int steps_per_chunk) {
  const int l = threadIdx.x;
  const int r = l & 15;        // A-frag row / adj row within tile
  const int g = l >> 4;        // k-group
  const int kb = g * 8;        // k base within 32-step
  const int row_base = blockIdx.x * 16;
  const int split = blockIdx.y;

  const float msum = dec_f32(maxbits[0]) + dec_f32(maxbits[1]);
  const float m = fmaxf(msum, 0.2f * msum);  // leaky(max s1 + max s2) >= all e

  int sb = split * steps_per_chunk;
  int se = sb + steps_per_chunk;
  if (se > TOTAL_STEPS) se = TOTAL_STEPS;
  bool has_tail = false;
  if (se == TOTAL_STEPS) { has_tail = true; se = TOTAL_STEPS - 1; }

  const float s1r = s1[row_base + r];
  const int* __restrict__ adjp = adj + (size_t)(row_base + r) * N_NODES;
  const unsigned short* __restrict__ bp = hbT + (size_t)r * NP;

  short8 ones_s;
#pragma unroll
  for (int e = 0; e < 8; ++e) ones_s[e] = (short)0x3F80;  // bf16 1.0
  const bf16x8 onesv = __builtin_bit_cast(bf16x8, ones_s);

  f32x4 acc0 = {0.f, 0.f, 0.f, 0.f};
  f32x4 acc1 = {0.f, 0.f, 0.f, 0.f};
  f32x4 acc2 = {0.f, 0.f, 0.f, 0.f};
  f32x4 acc3 = {0.f, 0.f, 0.f, 0.f};
  f32x4 accd = {0.f, 0.f, 0.f, 0.f};

#define LOADS(T, a0_, a1_, s0_, s1_, b0_, b1_, b2_, b3_) do {                \
    const int jj_ = (T) * 32 + kb;                                           \
    a0_ = *(const int4*)(adjp + jj_);                                        \
    a1_ = *(const int4*)(adjp + jj_ + 4);                                    \
    s0_ = *(const float4*)(s2 + jj_);                                        \
    s1_ = *(const float4*)(s2 + jj_ + 4);                                    \
    b0_ = *(const short8*)(bp + jj_);                                        \
    b1_ = *(const short8*)(bp + 16 * NP + jj_);                              \
    b2_ = *(const short8*)(bp + 32 * NP + jj_);                              \
    b3_ = *(const short8*)(bp + 48 * NP + jj_);                              \
  } while (0)

#define STEPC(a0_, a1_, s0_, s1_, b0_, b1_, b2_, b3_) do {                   \
    uint4v au_;                                                              \
    au_.x = wpair(s1r, s0_.x, s0_.y, a0_.x, a0_.y, m);                       \
    au_.y = wpair(s1r, s0_.z, s0_.w, a0_.z, a0_.w, m);                       \
    au_.z = wpair(s1r, s1_.x, s1_.y, a1_.x, a1_.y, m);                       \
    au_.w = wpair(s1r, s1_.z, s1_.w, a1_.z, a1_.w, m);                       \
    bf16x8 av_ = __builtin_bit_cast(bf16x8, au_);                            \
    acc0 = __builtin_amdgcn_mfma_f32_16x16x32_bf16(av_, __builtin_bit_cast(bf16x8, b0_), acc0, 0, 0, 0); \
    acc1 = __builtin_amdgcn_mfma_f32_16x16x32_bf16(av_, __builtin_bit_cast(bf16x8, b1_), acc1, 0, 0, 0); \
    acc2 = __builtin_amdgcn_mfma_f32_16x16x32_bf16(av_, __builtin_bit_cast(bf16x8, b2_), acc2, 0, 0, 0); \
    acc3 = __builtin_amdgcn_mfma_f32_16x16x32_bf16(av_, __builtin_bit_cast(bf16x8, b3_), acc3, 0, 0, 0); \
    accd = __builtin_amdgcn_mfma_f32_16x16x32_bf16(av_, onesv, accd, 0, 0, 0); \
  } while (0)

  int4 Aa0, Aa1; float4 As0, As1; short8 Ab0, Ab1, Ab2, Ab3;
  int4 Ba0, Ba1; float4 Bs0, Bs1; short8 Bb0, Bb1, Bb2, Bb3;

  int t = sb;
  if (se > sb) {
    LOADS(t, Aa0, Aa1, As0, As1, Ab0, Ab1, Ab2, Ab3);
    for (; t + 2 < se; t += 2) {
      LOADS(t + 1, Ba0, Ba1, Bs0, Bs1, Bb0, Bb1, Bb2, Bb3);
      STEPC(Aa0, Aa1, As0, As1, Ab0, Ab1, Ab2, Ab3);
      LOADS(t + 2, Aa0, Aa1, As0, As1, Ab0, Ab1, Ab2, Ab3);
      STEPC(Ba0, Ba1, Bs0, Bs1, Bb0, Bb1, Bb2, Bb3);
    }
    if (se - t == 2) {
      LOADS(t + 1, Ba0, Ba1, Bs0, Bs1, Bb0, Bb1, Bb2, Bb3);
      STEPC(Aa0, Aa1, As0, As1, Ab0, Ab1, Ab2, Ab3);
      STEPC(Ba0, Ba1, Bs0, Bs1, Bb0, Bb1, Bb2, Bb3);
    } else {
      STEPC(Aa0, Aa1, As0, As1, Ab0, Ab1, Ab2, Ab3);
    }
  }

  if (has_tail) {  // j0 = 9984: only 16 valid j -> k-groups 0,1 active
    uint4v au_ = {0u, 0u, 0u, 0u};
    short8 tb0 = {0,0,0,0,0,0,0,0}, tb1 = {0,0,0,0,0,0,0,0};
    short8 tb2 = {0,0,0,0,0,0,0,0}, tb3 = {0,0,0,0,0,0,0,0};
    if (g < 2) {
      const int jj_ = 9984 + kb;
      int4 ta0 = *(const int4*)(adjp + jj_);
      int4 ta1 = *(const int4*)(adjp + jj_ + 4);
      float4 ts0 = *(const float4*)(s2 + jj_);
      float4 ts1 = *(const float4*)(s2 + jj_ + 4);
      tb0 = *(const short8*)(bp + jj_);
      tb1 = *(const short8*)(bp + 16 * NP + jj_);
      tb2 = *(const short8*)(bp + 32 * NP + jj_);
      tb3 = *(const short8*)(bp + 48 * NP + jj_);
      au_.x = wpair(s1r, ts0.x, ts0.y, ta0.x, ta0.y, m);
      au_.y = wpair(s1r, ts0.z, ts0.w, ta0.z, ta0.w, m);
      au_.z = wpair(s1r, ts1.x, ts1.y, ta1.x, ta1.y, m);
      au_.w = wpair(s1r, ts1.z, ts1.w, ta1.z, ta1.w, m);
    }
    bf16x8 av_ = __builtin_bit_cast(bf16x8, au_);
    acc0 = __builtin_amdgcn_mfma_f32_16x16x32_bf16(av_, __builtin_bit_cast(bf16x8, tb0), acc0, 0, 0, 0);
    acc1 = __builtin_amdgcn_mfma_f32_16x16x32_bf16(av_, __builtin_bit_cast(bf16x8, tb1), acc1, 0, 0, 0);
    acc2 = __builtin_amdgcn_mfma_f32_16x16x32_bf16(av_, __builtin_bit_cast(bf16x8, tb2), acc2, 0, 0, 0);
    acc3 = __builtin_amdgcn_mfma_f32_16x16x32_bf16(av_, __builtin_bit_cast(bf16x8, tb3), acc3, 0, 0, 0);
    accd = __builtin_amdgcn_mfma_f32_16x16x32_bf16(av_, onesv, accd, 0, 0, 0);
  }

#undef LOADS
#undef STEPC

  // denominator: C/D col = l&15 (all cols equal), row = g*4 + q; lanes with r==0 write
  if (r == 0) {
#pragma unroll
    for (int q = 0; q < 4; ++q)
      den_part[(size_t)split * N_NODES + row_base + g * 4 + q] = accd[q];
  }

  // numerator: C/D layout col = l&15 (+16n), row = g*4 + q
  float* np_ = num_part + ((size_t)split * N_NODES + row_base) * FOUT;
#pragma unroll
  for (int q = 0; q < 4; ++q) {
    const int orow = g * 4 + q;
    np_[orow * FOUT + 0 + r] = acc0[q];
    np_[orow * FOUT + 16 + r] = acc1[q];
    np_[orow * FOUT + 32 + r] = acc2[q];
    np_[orow * FOUT + 48 + r] = acc3[q];
  }
}

// ---------------- Kernel C: reduce partials, normalize, ELU ----------------
__global__ __launch_bounds__(256) void gat_out(
    const float* __restrict__ num_part, const float* __restrict__ den_part,
    const unsigned short* __restrict__ hbT, float* __restrict__ out, int S) {
  const int idx = blockIdx.x * 256 + threadIdx.x;
  if (idx >= N_NODES * FOUT) return;
  const int i = idx >> 6, f = idx & 63;
  float den = 0.f, num = 0.f;
  for (int s = 0; s < S; ++s) {
    den += den_part[(size_t)s * N_NODES + i];
    num += num_part[(size_t)s * N_NODES * FOUT + idx];
  }
  float v;
  if (den > 0.f) {
    v = num / den;
  } else {
    // row with no neighbors: softmax(all NEG_BIG) = uniform -> mean of h
    float sum = 0.f;
    for (int j = 0; j < N_NODES; ++j) sum += bf2f(hbT[(size_t)f * NP + j]);
    v = sum / (float)N_NODES;
  }
  out[idx] = (v > 0.f) ? v : (__expf(v) - 1.f);
}

extern "C" void kernel_launch(void* const* d_in, const int* in_sizes, int n_in,
                              void* d_out, int out_size, void* d_ws, size_t ws_size,
                              hipStream_t stream) {
  const float* input = (const float*)d_in[0];
  const float* W = (const float*)d_in[1];
  const float* a = (const float*)d_in[2];
  const int* adj = (const int*)d_in[3];
  float* out = (float*)d_out;

  const size_t fixed = 64 + (size_t)N_NODES * 4 + (size_t)NP * 4 + (size_t)FOUT * NP * 2 + 256;
  int S = 8;
  if (ws_size < fixed + (size_t)8 * N_NODES * (FOUT * 4 + 4)) S = 4;
  if (ws_size < fixed + (size_t)4 * N_NODES * (FOUT * 4 + 4)) S = 1;

  char* p = (char*)d_ws;
  unsigned int* maxbits = (unsigned int*)p;  p += 64;
  float* s1 = (float*)p;                     p += (size_t)N_NODES * 4;
  float* s2 = (float*)p;                     p += (size_t)NP * 4;
  unsigned short* hbT = (unsigned short*)p;  p += (size_t)FOUT * NP * 2;
  float* num_part = (float*)p;               p += (size_t)S * N_NODES * FOUT * 4;
  float* den_part = (float*)p;

  // only maxbits needs zero-init; num/den partials are fully overwritten
  (void)hipMemsetAsync(maxbits, 0, 8, stream);

  hipLaunchKernelGGL(gat_h, dim3(N_NODES / 8), dim3(64), 0, stream,
                     input, W, a, s1, s2, hbT, maxbits);

  int steps_per_chunk = (TOTAL_STEPS + S - 1) / S;
  hipLaunchKernelGGL(gat_attn, dim3(N_NODES / 16, S), dim3(64), 0, stream,
                     adj, s1, s2, hbT, maxbits, num_part, den_part, steps_per_chunk);

  hipLaunchKernelGGL(gat_out, dim3((N_NODES * FOUT + 255) / 256), dim3(256), 0, stream,
                     num_part, den_part, hbT, out, S);
}

// Round 4
// 665.604 us; speedup vs baseline: 1.0287x; 1.0163x over previous
//
#include <hip/hip_runtime.h>
#include <hip/hip_bf16.h>

#define N_NODES 10000
#define FIN 512
#define FOUT 64
#define NP 10016            // padded row length for h^T (bf16) and s2
#define TOTAL_STEPS 313     // ceil(10000/32); step 312 is the 16-wide tail
#define N_TILES 625         // 10000 / 16
#define SPLITS 8

typedef __attribute__((ext_vector_type(8))) short short8;
typedef __attribute__((ext_vector_type(4))) float f32x4;
typedef __attribute__((ext_vector_type(8))) __bf16 bf16x8;
typedef __attribute__((ext_vector_type(4))) unsigned int uint4v;

static __device__ __forceinline__ unsigned short f2bf(float f) {
  unsigned u = __builtin_bit_cast(unsigned, f);
  u += 0x7FFFu + ((u >> 16) & 1u);          // RNE
  return (unsigned short)(u >> 16);
}
static __device__ __forceinline__ float bf2f(unsigned short s) {
  unsigned u = ((unsigned)s) << 16;
  return __builtin_bit_cast(float, u);
}
// order-preserving f32 -> u32 map (for atomicMax); memset-0 init == below everything
static __device__ __forceinline__ unsigned enc_f32(float f) {
  unsigned u = __builtin_bit_cast(unsigned, f);
  return (u & 0x80000000u) ? ~u : (u | 0x80000000u);
}
static __device__ __forceinline__ float dec_f32(unsigned u) {
  unsigned b = (u & 0x80000000u) ? (u & 0x7FFFFFFFu) : ~u;
  return __builtin_bit_cast(float, b);
}

// weight pair: leaky_relu via max(x, 0.2x); mask via select; RNE pack into u32
static __device__ __forceinline__ unsigned wpair(float s1r, float sA, float sB,
                                                 int adA, int adB, float m) {
  float eA = s1r + sA, eB = s1r + sB;
  eA = fmaxf(eA, 0.2f * eA);
  eB = fmaxf(eB, 0.2f * eB);
  float wA = (adA > 0) ? __expf(eA - m) : 0.f;
  float wB = (adB > 0) ? __expf(eB - m) : 0.f;
  return ((unsigned)f2bf(wB) << 16) | (unsigned)f2bf(wA);
}

// ---------------- Kernel A: h = X@W (fp32), s1=h@a1, s2=h@a2, h^T in bf16 ----------------
__global__ __launch_bounds__(64) void gat_h(
    const float* __restrict__ input, const float* __restrict__ W,
    const float* __restrict__ a, float* __restrict__ s1,
    float* __restrict__ s2, unsigned short* __restrict__ hbT,
    unsigned int* __restrict__ maxbits) {
  __shared__ float in_lds[8 * FIN];
  const int l = threadIdx.x;
  const int rb = blockIdx.x * 8;

  const float4* src = (const float4*)(input + (size_t)rb * FIN);
  float4* dst = (float4*)in_lds;
#pragma unroll
  for (int v = 0; v < 16; ++v) dst[l + 64 * v] = src[l + 64 * v];
  __syncthreads();

  float acc[8] = {0.f, 0.f, 0.f, 0.f, 0.f, 0.f, 0.f, 0.f};
  for (int k4 = 0; k4 < FIN / 4; ++k4) {
    float w0 = W[(k4 * 4 + 0) * FOUT + l];
    float w1 = W[(k4 * 4 + 1) * FOUT + l];
    float w2 = W[(k4 * 4 + 2) * FOUT + l];
    float w3 = W[(k4 * 4 + 3) * FOUT + l];
#pragma unroll
    for (int r = 0; r < 8; ++r) {
      float4 iv = *(const float4*)&in_lds[r * FIN + k4 * 4];  // uniform LDS broadcast
      acc[r] = fmaf(iv.x, w0, fmaf(iv.y, w1, fmaf(iv.z, w2, fmaf(iv.w, w3, acc[r]))));
    }
  }

  short8 pk;
#pragma unroll
  for (int r = 0; r < 8; ++r) pk[r] = (short)f2bf(acc[r]);
  *(short8*)(hbT + (size_t)l * NP + rb) = pk;

  const float a1l = a[l], a2l = a[FOUT + l];
  float m1 = -1e30f, m2 = -1e30f;
#pragma unroll
  for (int r = 0; r < 8; ++r) {
    float v1 = acc[r] * a1l, v2 = acc[r] * a2l;
#pragma unroll
    for (int off = 32; off > 0; off >>= 1) {
      v1 += __shfl_xor(v1, off);
      v2 += __shfl_xor(v2, off);
    }
    if (l == 0) { s1[rb + r] = v1; s2[rb + r] = v2; }
    m1 = fmaxf(m1, v1);
    m2 = fmaxf(m2, v2);
  }
  if (l == 0) {
    atomicMax(maxbits + 0, enc_f32(m1));
    atomicMax(maxbits + 1, enc_f32(m2));
  }
}

// ---------------- Kernel B: fused masked-softmax x h (the 400 MB adj stream) ----------------
// 4 waves per block (each wave = one 16-row tile); blockIdx.y = K-split chunk.
// No manual prefetch: 8 waves/SIMD TLP hides HBM latency; VGPR capped at 64.
__global__ __launch_bounds__(256, 8) void gat_attn(
    const int* __restrict__ adj, const float* __restrict__ s1,
    const float* __restrict__ s2, const unsigned short* __restrict__ hbT,
    const unsigned int* __restrict__ maxbits,
    float* __restrict__ num_part, float* __restrict__ den_part,
    int steps_per_chunk) {
  const int tid = threadIdx.x;
  const int wave = tid >> 6;
  const int l = tid & 63;
  const int tile = blockIdx.x * 4 + wave;
  if (tile >= N_TILES) return;

  const int r = l & 15;        // A-frag row / adj row within tile
  const int g = l >> 4;        // k-group
  const int kb = g * 8;        // k base within 32-step
  const int row_base = tile * 16;
  const int split = blockIdx.y;

  const float msum = dec_f32(maxbits[0]) + dec_f32(maxbits[1]);
  const float m = fmaxf(msum, 0.2f * msum);  // leaky(max s1 + max s2) >= all e

  int sb = split * steps_per_chunk;
  int se = sb + steps_per_chunk;
  if (se > TOTAL_STEPS) se = TOTAL_STEPS;
  bool has_tail = false;
  if (se == TOTAL_STEPS) { has_tail = true; se = TOTAL_STEPS - 1; }

  const float s1r = s1[row_base + r];
  const int* __restrict__ adjp = adj + (size_t)(row_base + r) * N_NODES;
  const unsigned short* __restrict__ bp = hbT + (size_t)r * NP;

  short8 ones_s;
#pragma unroll
  for (int e = 0; e < 8; ++e) ones_s[e] = (short)0x3F80;  // bf16 1.0
  const bf16x8 onesv = __builtin_bit_cast(bf16x8, ones_s);

  f32x4 acc0 = {0.f, 0.f, 0.f, 0.f};
  f32x4 acc1 = {0.f, 0.f, 0.f, 0.f};
  f32x4 acc2 = {0.f, 0.f, 0.f, 0.f};
  f32x4 acc3 = {0.f, 0.f, 0.f, 0.f};
  f32x4 accd = {0.f, 0.f, 0.f, 0.f};

  for (int t = sb; t < se; ++t) {
    const int j = t * 32 + kb;
    int4 a0 = *(const int4*)(adjp + j);
    int4 a1 = *(const int4*)(adjp + j + 4);
    float4 s0 = *(const float4*)(s2 + j);
    float4 sv = *(const float4*)(s2 + j + 4);
    uint4v au;
    au.x = wpair(s1r, s0.x, s0.y, a0.x, a0.y, m);
    au.y = wpair(s1r, s0.z, s0.w, a0.z, a0.w, m);
    au.z = wpair(s1r, sv.x, sv.y, a1.x, a1.y, m);
    au.w = wpair(s1r, sv.z, sv.w, a1.z, a1.w, m);
    bf16x8 av = __builtin_bit_cast(bf16x8, au);
    short8 b0 = *(const short8*)(bp + j);
    short8 b1 = *(const short8*)(bp + 16 * NP + j);
    short8 b2 = *(const short8*)(bp + 32 * NP + j);
    short8 b3 = *(const short8*)(bp + 48 * NP + j);
    acc0 = __builtin_amdgcn_mfma_f32_16x16x32_bf16(av, __builtin_bit_cast(bf16x8, b0), acc0, 0, 0, 0);
    acc1 = __builtin_amdgcn_mfma_f32_16x16x32_bf16(av, __builtin_bit_cast(bf16x8, b1), acc1, 0, 0, 0);
    acc2 = __builtin_amdgcn_mfma_f32_16x16x32_bf16(av, __builtin_bit_cast(bf16x8, b2), acc2, 0, 0, 0);
    acc3 = __builtin_amdgcn_mfma_f32_16x16x32_bf16(av, __builtin_bit_cast(bf16x8, b3), acc3, 0, 0, 0);
    accd = __builtin_amdgcn_mfma_f32_16x16x32_bf16(av, onesv, accd, 0, 0, 0);
  }

  if (has_tail) {  // j0 = 9984: only 16 valid j -> k-groups 0,1 active
    uint4v au = {0u, 0u, 0u, 0u};
    short8 b0 = {0,0,0,0,0,0,0,0}, b1 = {0,0,0,0,0,0,0,0};
    short8 b2 = {0,0,0,0,0,0,0,0}, b3 = {0,0,0,0,0,0,0,0};
    if (g < 2) {
      const int j = 9984 + kb;
      int4 a0 = *(const int4*)(adjp + j);
      int4 a1 = *(const int4*)(adjp + j + 4);
      float4 s0 = *(const float4*)(s2 + j);
      float4 sv = *(const float4*)(s2 + j + 4);
      b0 = *(const short8*)(bp + j);
      b1 = *(const short8*)(bp + 16 * NP + j);
      b2 = *(const short8*)(bp + 32 * NP + j);
      b3 = *(const short8*)(bp + 48 * NP + j);
      au.x = wpair(s1r, s0.x, s0.y, a0.x, a0.y, m);
      au.y = wpair(s1r, s0.z, s0.w, a0.z, a0.w, m);
      au.z = wpair(s1r, sv.x, sv.y, a1.x, a1.y, m);
      au.w = wpair(s1r, sv.z, sv.w, a1.z, a1.w, m);
    }
    bf16x8 av = __builtin_bit_cast(bf16x8, au);
    acc0 = __builtin_amdgcn_mfma_f32_16x16x32_bf16(av, __builtin_bit_cast(bf16x8, b0), acc0, 0, 0, 0);
    acc1 = __builtin_amdgcn_mfma_f32_16x16x32_bf16(av, __builtin_bit_cast(bf16x8, b1), acc1, 0, 0, 0);
    acc2 = __builtin_amdgcn_mfma_f32_16x16x32_bf16(av, __builtin_bit_cast(bf16x8, b2), acc2, 0, 0, 0);
    acc3 = __builtin_amdgcn_mfma_f32_16x16x32_bf16(av, __builtin_bit_cast(bf16x8, b3), acc3, 0, 0, 0);
    accd = __builtin_amdgcn_mfma_f32_16x16x32_bf16(av, onesv, accd, 0, 0, 0);
  }

  // denominator: C/D col = l&15 (all cols equal), row = g*4 + q; lanes with r==0 write
  if (r == 0) {
#pragma unroll
    for (int q = 0; q < 4; ++q)
      den_part[(size_t)split * N_NODES + row_base + g * 4 + q] = accd[q];
  }

  // numerator: C/D layout col = l&15 (+16n), row = g*4 + q
  float* np_ = num_part + ((size_t)split * N_NODES + row_base) * FOUT;
#pragma unroll
  for (int q = 0; q < 4; ++q) {
    const int orow = g * 4 + q;
    np_[orow * FOUT + 0 + r] = acc0[q];
    np_[orow * FOUT + 16 + r] = acc1[q];
    np_[orow * FOUT + 32 + r] = acc2[q];
    np_[orow * FOUT + 48 + r] = acc3[q];
  }
}

// ---------------- Kernel C: reduce partials, normalize, ELU (float4) ----------------
__global__ __launch_bounds__(256) void gat_out(
    const float* __restrict__ num_part, const float* __restrict__ den_part,
    const unsigned short* __restrict__ hbT, float* __restrict__ out, int S) {
  const int q = blockIdx.x * 256 + threadIdx.x;  // quad index; 16 quads per node row
  if (q >= N_NODES * FOUT / 4) return;
  const int i = q >> 4;
  const int f4 = (q & 15) * 4;
  float den = 0.f;
  float4 num = {0.f, 0.f, 0.f, 0.f};
  for (int s = 0; s < S; ++s) {
    den += den_part[(size_t)s * N_NODES + i];
    float4 v = *(const float4*)(num_part + ((size_t)s * N_NODES + i) * FOUT + f4);
    num.x += v.x; num.y += v.y; num.z += v.z; num.w += v.w;
  }
  float4 res;
  if (den > 0.f) {
    res.x = num.x / den; res.y = num.y / den; res.z = num.z / den; res.w = num.w / den;
  } else {
    // row with no neighbors: softmax(all NEG_BIG) = uniform -> mean of h (rare path)
    float s0 = 0.f, s1 = 0.f, s2 = 0.f, s3 = 0.f;
    for (int j = 0; j < N_NODES; ++j) {
      s0 += bf2f(hbT[(size_t)(f4 + 0) * NP + j]);
      s1 += bf2f(hbT[(size_t)(f4 + 1) * NP + j]);
      s2 += bf2f(hbT[(size_t)(f4 + 2) * NP + j]);
      s3 += bf2f(hbT[(size_t)(f4 + 3) * NP + j]);
    }
    res.x = s0 / (float)N_NODES; res.y = s1 / (float)N_NODES;
    res.z = s2 / (float)N_NODES; res.w = s3 / (float)N_NODES;
  }
  res.x = (res.x > 0.f) ? res.x : (__expf(res.x) - 1.f);
  res.y = (res.y > 0.f) ? res.y : (__expf(res.y) - 1.f);
  res.z = (res.z > 0.f) ? res.z : (__expf(res.z) - 1.f);
  res.w = (res.w > 0.f) ? res.w : (__expf(res.w) - 1.f);
  *(float4*)(out + (size_t)q * 4) = res;
}

extern "C" void kernel_launch(void* const* d_in, const int* in_sizes, int n_in,
                              void* d_out, int out_size, void* d_ws, size_t ws_size,
                              hipStream_t stream) {
  const float* input = (const float*)d_in[0];
  const float* W = (const float*)d_in[1];
  const float* a = (const float*)d_in[2];
  const int* adj = (const int*)d_in[3];
  float* out = (float*)d_out;

  const size_t fixed = 64 + (size_t)N_NODES * 4 + (size_t)NP * 4 + (size_t)FOUT * NP * 2 + 256;
  int S = SPLITS;
  if (ws_size < fixed + (size_t)SPLITS * N_NODES * (FOUT * 4 + 4)) S = 1;

  char* p = (char*)d_ws;
  unsigned int* maxbits = (unsigned int*)p;  p += 64;
  float* s1 = (float*)p;                     p += (size_t)N_NODES * 4;
  float* s2 = (float*)p;                     p += (size_t)NP * 4;
  unsigned short* hbT = (unsigned short*)p;  p += (size_t)FOUT * NP * 2;
  float* num_part = (float*)p;               p += (size_t)S * N_NODES * FOUT * 4;
  float* den_part = (float*)p;

  // only maxbits needs zero-init; num/den partials are fully overwritten
  (void)hipMemsetAsync(maxbits, 0, 8, stream);

  hipLaunchKernelGGL(gat_h, dim3(N_NODES / 8), dim3(64), 0, stream,
                     input, W, a, s1, s2, hbT, maxbits);

  int steps_per_chunk = (TOTAL_STEPS + S - 1) / S;
  hipLaunchKernelGGL(gat_attn, dim3((N_TILES + 3) / 4, S), dim3(256), 0, stream,
                     adj, s1, s2, hbT, maxbits, num_part, den_part, steps_per_chunk);

  hipLaunchKernelGGL(gat_out, dim3((N_NODES * FOUT / 4 + 255) / 256), dim3(256), 0, stream,
                     num_part, den_part, hbT, out, S);
}